// Round 19
// baseline (121.814 us; speedup 1.0000x reference)
//
#include <hip/hip_runtime.h>
#include <hip/hip_fp16.h>

// Problem constants: B=8, C=32, H=256, W=448, kernel_size=1
constexpr int B = 8;
constexpr int C = 32;
constexpr int H = 256;
constexpr int W = 448;
constexpr int HW = H * W;

// Output-centric tiling; one THREAD owns TWO output cells (qy and qy+8).
// A source is "handled" iff floor(p+flow)-p is in [-RAD, RAD-1] on both dims;
// unhandled in-image sources go to a compact outlier list in d_ws.
// R19 vs R18:
//  - Tile 64x8 -> 64x16 (1024 cells, NT=512, 2 cells/thread): window/cell
//    amplification 1.97x -> 1.55x (21% less geometry+staging globally).
//  - UNIFIED gather walk over the union of both cells' masks: wave-max
//    iterations ~ max(nA+nB) instead of max(nA)+max(nB) (~25% fewer
//    DS-read iterations -> attacks exec-mask divergence).
constexpr int TW  = 64;           // 448/64 = 7 tiles in x
constexpr int TH  = 16;           // 256/16 = 16 tiles in y
constexpr int RAD = 3;
constexpr int WXV = 72;           // window stride; gx in [ox-4, ox+68)
constexpr int WY  = TH + 2 * RAD; // 22
constexpr int NV  = WXV * WY;     // 1584
constexpr int NT  = 512;          // 2 cells per thread
constexpr int CELLS = TW * TH;    // 1024
constexpr int GITER = (NV + NT - 1) / NT;        // 4 (last iter partial)
constexpr int NG4 = (WXV / 4) * WY;              // 396 float4 col-groups
constexpr int NITEM16 = NG4 * 4;                 // 1584 items per 16-ch pass
constexpr int KIT16 = (NITEM16 + NT - 1) / NT;   // 4 (last iter partial)

static __device__ __forceinline__ unsigned pkrtz(float a, float b) {
    return __builtin_bit_cast(unsigned, __builtin_amdgcn_cvt_pkrtz(a, b));
}

static __device__ __forceinline__ __half2 h2(unsigned u) {
    union { unsigned u; __half2 h; } x;
    x.u = u;
    return x.h;
}

__global__ __launch_bounds__(NT)
void splat_out(const float* __restrict__ in1,
               const float* __restrict__ flow,
               float* __restrict__ out,
               unsigned* __restrict__ wcnt,
               unsigned* __restrict__ wlist,
               unsigned cap) {
    // mAllS[cell] bit j=(dy+3)*8+(dx+3): source at window offset (dx,dy)
    //   from the cell contributes (dx,dy = source - cell).
    // geomR8[i]: (rx+3) | (ry+3)<<3 (0xFF default, never consumed then).
    // geomW[i]: .x = half2(w00,w10), .y = half2(w01,w11).
    // valV2[pp*NV + i]: uint2 = channels (cb+4pp..cb+4pp+3) of source i for
    //   the current 16-channel pass, packed {pkrtz(c0,c1), pkrtz(c2,c3)}.
    __shared__ unsigned long long mAllS[CELLS];       // 8 KB
    __shared__ unsigned char     geomR8[NV];          // 1.6 KB
    __shared__ uint2             geomW[NV];           // 12.7 KB
    __shared__ __align__(16) uint2 valV2[4 * NV];     // 50.7 KB (total ~73 KB)

    int bid = blockIdx.x;
    int b = bid & 7;                 // batch -> XCD affinity
    int t = bid >> 3;                // 0..111
    int ty = t / 7;                  // 0..15
    int tx = t - ty * 7;             // 0..6
    int ox = tx * TW, oy = ty * TH;
    int tid = threadIdx.x;
    int qlx = tid & 63, qly = tid >> 6;   // qly in 0..7; cells (qly, qly+8)
    int qx = ox + qlx, qy = oy + qly;

    mAllS[tid]       = 0ull;
    mAllS[tid + NT]  = 0ull;
    __syncthreads();

    // ---- geometry + 1-mask scatter (once per source) + outlier append ----
    const int fbase = b * 2 * HW;
#pragma unroll
    for (int k = 0; k < GITER; ++k) {
        int i = tid + k * NT;
        if (i < NV) {
            int wy = i / WXV, wv = i - wy * WXV;
            int gx = ox + wv - 4;            // window x-origin is ox-4
            int sy = oy + wy - RAD;
            uint2 wd = make_uint2(0u, 0u);
            unsigned gr = 0xFFu;
            if ((unsigned)gx < (unsigned)W && (unsigned)sy < (unsigned)H) {
                int g = sy * W + gx;
                float u = flow[fbase + g];
                float v = flow[fbase + g + HW];
                float txf = (float)gx + u;
                float tyf = (float)sy + v;
                float x0f = floorf(txf), y0f = floorf(tyf);
                int rx = (int)x0f - gx, ry = (int)y0f - sy;
                if (rx >= -RAD && rx <= RAD - 1 && ry >= -RAD && ry <= RAD - 1) {
                    float fx = txf - x0f, fy = tyf - y0f;
                    wd.x = pkrtz((1.f - fx) * (1.f - fy), fx * (1.f - fy));
                    wd.y = pkrtz((1.f - fx) * fy,         fx * fy);
                    gr = (unsigned)(rx + RAD) | ((unsigned)(ry + RAD) << 3);
                    // scatter the 4 corners into target cells' masks
#pragma unroll
                    for (int corner = 0; corner < 4; ++corner) {
                        int dxx = corner & 1, dyy = corner >> 1;
                        int ccx = gx + rx + dxx - ox;    // cell tile coords
                        int ccy = sy + ry + dyy - oy;
                        if ((unsigned)ccx < (unsigned)TW &&
                            (unsigned)ccy < (unsigned)TH) {
                            int cell = ccy * TW + ccx;
                            unsigned long long bit =
                                1ull << ((3 - (ry + dyy)) * 8 + (3 - (rx + dxx)));
                            atomicOr(&mAllS[cell], bit);
                        }
                    }
                } else if (wv >= 4 && wv < 4 + TW &&
                           wy >= RAD && wy < RAD + TH) {
                    // unhandled source OWNED by this tile: append exactly once
                    unsigned slot = atomicAdd(wcnt, 1u);
                    if (slot < cap) wlist[slot] = ((unsigned)b << 17) | (unsigned)g;
                }
            }
            geomR8[i] = (unsigned char)gr;
            geomW[i]  = wd;
        }
    }

    const float* inb = in1 + (size_t)b * C * HW;

    // stage 16 channels of pass p (channels 16p .. 16p+15)
    auto stage16 = [&](int pass) {
#pragma unroll
        for (int k = 0; k < KIT16; ++k) {
            int id = tid + k * NT;
            if (id < NITEM16) {
                int g4 = id % NG4;           // float4 column group
                int pp = id / NG4;           // plane pair 0..3
                int wy = g4 / (WXV / 4);
                int wv4 = (g4 - wy * (WXV / 4)) * 4;
                int row = min(max(oy + wy - RAD, 0), H - 1);
                int gxb = min(max(ox + wv4 - 4, 0), W - 4);
                // group base 4-aligned; groups fully in- or out-of-image, and
                // out-of-image cells are never consumed -> clamp is exact.
                const float* base = inb + (size_t)(16 * pass + 4 * pp) * HW
                                        + (size_t)row * W + gxb;
                float4 c0 = *reinterpret_cast<const float4*>(base);
                float4 c1 = *reinterpret_cast<const float4*>(base + (size_t)HW);
                float4 c2 = *reinterpret_cast<const float4*>(base + (size_t)2 * HW);
                float4 c3 = *reinterpret_cast<const float4*>(base + (size_t)3 * HW);
                int vbase = pp * NV + wy * WXV + wv4;    // even -> 16B aligned
                uint4* dst = reinterpret_cast<uint4*>(&valV2[vbase]);
                uint4 w0, w1;
                w0.x = pkrtz(c0.x, c1.x); w0.y = pkrtz(c2.x, c3.x);
                w0.z = pkrtz(c0.y, c1.y); w0.w = pkrtz(c2.y, c3.y);
                w1.x = pkrtz(c0.z, c1.z); w1.y = pkrtz(c2.z, c3.z);
                w1.z = pkrtz(c0.w, c1.w); w1.w = pkrtz(c2.w, c3.w);
                dst[0] = w0;
                dst[1] = w1;
            }
        }
    };

    stage16(0);
    __syncthreads();

    const int qbA = (qly + RAD) * WXV + (qlx + 4);          // cell tid
    const int qbB = (qly + 8 + RAD) * WXV + (qlx + 4);      // cell tid+512
    float* outp = out + (size_t)b * C * HW + qy * W + qx;   // cell A
    // cell B output = outp + 8*W within each plane.

    // ---- unified gather over BOTH cells' masks (16 channels) ----
    auto gather16 = [&](float* oA) {
        __half2 aA[8], aB[8];
#pragma unroll
        for (int k = 0; k < 8; ++k) { aA[k] = h2(0u); aB[k] = h2(0u); }
        unsigned long long mA = mAllS[tid];
        unsigned long long mB = mAllS[tid + NT];
        while (mA | mB) {
            bool useB = (mA == 0ull);
            unsigned long long mm = useB ? mB : mA;
            int j = (int)__builtin_ctzll(mm);
            mm &= mm - 1;
            if (useB) mB = mm; else mA = mm;
            int qb = useB ? qbB : qbA;
            int wi = qb + ((j >> 3) - 3) * WXV + ((j & 7) - 3);
            unsigned g8 = geomR8[wi];
            unsigned dxx = 6u - (unsigned)(j & 7) - (g8 & 7u);   // in {0,1}
            unsigned dyy = 6u - (unsigned)(j >> 3) - (g8 >> 3);  // in {0,1}
            uint2 wd2 = geomW[wi];
            unsigned wd = dyy ? wd2.y : wd2.x;
            unsigned hq = (wd >> (16u * dxx)) & 0xFFFFu;
            __half2 w2 = h2(hq | (hq << 16));
            if (useB) {
#pragma unroll
                for (int pp = 0; pp < 4; ++pp) {
                    uint2 vv = valV2[pp * NV + wi];
                    aB[2 * pp + 0] = __hfma2(h2(vv.x), w2, aB[2 * pp + 0]);
                    aB[2 * pp + 1] = __hfma2(h2(vv.y), w2, aB[2 * pp + 1]);
                }
            } else {
#pragma unroll
                for (int pp = 0; pp < 4; ++pp) {
                    uint2 vv = valV2[pp * NV + wi];
                    aA[2 * pp + 0] = __hfma2(h2(vv.x), w2, aA[2 * pp + 0]);
                    aA[2 * pp + 1] = __hfma2(h2(vv.y), w2, aA[2 * pp + 1]);
                }
            }
        }
        float* oB = oA + (size_t)8 * W;
#pragma unroll
        for (int pp = 0; pp < 4; ++pp) {
            float2 a01 = __half22float2(aA[2 * pp + 0]);
            float2 a23 = __half22float2(aA[2 * pp + 1]);
            float2 b01 = __half22float2(aB[2 * pp + 0]);
            float2 b23 = __half22float2(aB[2 * pp + 1]);
            oA[(size_t)(4 * pp + 0) * HW] = a01.x;
            oA[(size_t)(4 * pp + 1) * HW] = a01.y;
            oA[(size_t)(4 * pp + 2) * HW] = a23.x;
            oA[(size_t)(4 * pp + 3) * HW] = a23.y;
            oB[(size_t)(4 * pp + 0) * HW] = b01.x;
            oB[(size_t)(4 * pp + 1) * HW] = b01.y;
            oB[(size_t)(4 * pp + 2) * HW] = b23.x;
            oB[(size_t)(4 * pp + 3) * HW] = b23.y;
        }
    };

    gather16(outp);                          // channels 0..15
    __syncthreads();
    stage16(1);
    __syncthreads();
    gather16(outp + (size_t)16 * HW);        // channels 16..31
}

// Outlier handling: list mode if the d_ws list didn't overflow, else full
// scan. Runs AFTER splat_out in stream order -> atomicAdds on plain stores.
__global__ void outlier_combined(const float* __restrict__ in1,
                                 const float* __restrict__ flow,
                                 float* __restrict__ out,
                                 const unsigned* __restrict__ wcnt,
                                 const unsigned* __restrict__ wlist,
                                 unsigned cap) {
    unsigned n = *wcnt;
    if (n <= cap) {
        // ---- list mode: 8 threads per entry (4 channels each) ----
        unsigned total = n * 8u;
        for (unsigned idx = blockIdx.x * blockDim.x + threadIdx.x;
             idx < total; idx += gridDim.x * blockDim.x) {
            unsigned e = wlist[idx >> 3];
            int c0 = (int)(idx & 7u) * 4;
            int bb = (int)(e >> 17);
            int p  = (int)(e & 0x1FFFFu);
            int y = p / W, x = p - y * W;

            float u = flow[(bb * 2 + 0) * HW + p];
            float v = flow[(bb * 2 + 1) * HW + p];
            float txf = (float)x + u;
            float tyf = (float)y + v;
            float fx0 = floorf(txf), fy0 = floorf(tyf);
            int x0 = (int)fx0, y0 = (int)fy0;
            float fx = txf - fx0, fy = tyf - fy0;
            float w00 = (1.0f - fx) * (1.0f - fy);
            float w10 = fx * (1.0f - fy);
            float w01 = (1.0f - fx) * fy;
            float w11 = fx * fy;
            bool vx0 = (x0 >= 0) && (x0 < W);
            bool vx1 = (x0 + 1 >= 0) && (x0 + 1 < W);
            bool vy0 = (y0 >= 0) && (y0 < H);
            bool vy1 = (y0 + 1 >= 0) && (y0 + 1 < H);
            long o00 = (long)y0 * W + x0;

            const float* src  = in1 + (size_t)bb * C * HW + (size_t)c0 * HW + p;
            float*       dstb = out + (size_t)bb * C * HW + (size_t)c0 * HW;
            for (int c = 0; c < 4; ++c) {
                float val = src[(size_t)c * HW];
                float* ob = dstb + (size_t)c * HW;
                if (vx0 && vy0) atomicAdd(ob + o00,         w00 * val);
                if (vx1 && vy0) atomicAdd(ob + o00 + 1,     w10 * val);
                if (vx0 && vy1) atomicAdd(ob + o00 + W,     w01 * val);
                if (vx1 && vy1) atomicAdd(ob + o00 + W + 1, w11 * val);
            }
        }
    } else {
        // ---- fallback: deterministic full scan (list overflowed) ----
        int npix = B * HW;
        for (int idx = blockIdx.x * blockDim.x + threadIdx.x;
             idx < npix; idx += gridDim.x * blockDim.x) {
            int b = idx / HW;
            int p = idx - b * HW;
            int y = p / W, x = p - y * W;
            float u = flow[(b * 2 + 0) * HW + p];
            float v = flow[(b * 2 + 1) * HW + p];
            float txf = (float)x + u;
            float tyf = (float)y + v;
            float fx0 = floorf(txf), fy0 = floorf(tyf);
            int x0 = (int)fx0, y0 = (int)fy0;
            int rx = x0 - x, ry = y0 - y;
            bool handled = (rx >= -RAD) && (rx <= RAD - 1) &&
                           (ry >= -RAD) && (ry <= RAD - 1);
            if (handled) continue;
            float fx = txf - fx0, fy = tyf - fy0;
            float w00 = (1.0f - fx) * (1.0f - fy);
            float w10 = fx * (1.0f - fy);
            float w01 = (1.0f - fx) * fy;
            float w11 = fx * fy;
            bool vx0 = (x0 >= 0) && (x0 < W);
            bool vx1 = (x0 + 1 >= 0) && (x0 + 1 < W);
            bool vy0 = (y0 >= 0) && (y0 < H);
            bool vy1 = (y0 + 1 >= 0) && (y0 + 1 < H);
            long o00 = (long)y0 * W + x0;
            const float* src = in1 + (size_t)b * C * HW + p;
            float* dstb = out + (size_t)b * C * HW;
            for (int c = 0; c < C; ++c) {
                float val = src[(size_t)c * HW];
                float* ob = dstb + (size_t)c * HW;
                if (vx0 && vy0) atomicAdd(ob + o00,         w00 * val);
                if (vx1 && vy0) atomicAdd(ob + o00 + 1,     w10 * val);
                if (vx0 && vy1) atomicAdd(ob + o00 + W,     w01 * val);
                if (vx1 && vy1) atomicAdd(ob + o00 + W + 1, w11 * val);
            }
        }
    }
}

extern "C" void kernel_launch(void* const* d_in, const int* in_sizes, int n_in,
                              void* d_out, int out_size, void* d_ws, size_t ws_size,
                              hipStream_t stream) {
    const float* in1  = (const float*)d_in[0];
    const float* flow = (const float*)d_in[1];
    float* out = (float*)d_out;

    unsigned* wcnt  = (unsigned*)d_ws;
    unsigned* wlist = wcnt + 4;   // 16B-aligned list start
    unsigned cap = 0;
    if (ws_size >= 64) {
        size_t c = ws_size / sizeof(unsigned) - 4;
        cap = (c > 0x7FFFFFFFull) ? 0x7FFFFFFFu : (unsigned)c;
    }

    hipMemsetAsync(wcnt, 0, sizeof(unsigned), stream);

    int nblocks = B * (H / TH) * (W / TW);   // 8 * 16 * 7 = 896
    splat_out<<<nblocks, NT, 0, stream>>>(in1, flow, out, wcnt, wlist, cap);

    outlier_combined<<<256, 256, 0, stream>>>(in1, flow, out, wcnt, wlist, cap);
}

// Round 20
// 107.843 us; speedup vs baseline: 1.1295x; 1.1295x over previous
//
#include <hip/hip_runtime.h>
#include <hip/hip_fp16.h>

// Problem constants: B=8, C=32, H=256, W=448, kernel_size=1
constexpr int B = 8;
constexpr int C = 32;
constexpr int H = 256;
constexpr int W = 448;
constexpr int HW = H * W;

// Output-centric tiling; one thread per output cell. A source is "handled"
// iff floor(p+flow)-p is in [-RAD, RAD-1] on both dims; unhandled in-image
// sources go to a compact outlier list in d_ws (processed by a 2nd kernel).
// R20 = revert to R18 (best measured: splat_out ~91 us, total ~108 us).
// R19's bigger tile + unified walk regressed (106 us) -> pre-committed stop.
//  - pass-0 staging values preloaded into REGISTERS at kernel top (addresses
//    are block-static) -> HBM latency partially hides under geometry+scatter;
//  - two 16-channel passes; pass-1 global loads issued BEFORE gather-0;
//  - valV 32.3 KB -> total LDS ~45 KB.
constexpr int TW  = 64;           // 448/64 = 7 tiles in x
constexpr int TH  = 8;            // 256/8  = 32 tiles in y
constexpr int RAD = 3;
constexpr int WXV = 72;           // window stride; gx in [ox-4, ox+68)
constexpr int WY  = TH + 2 * RAD; // 14
constexpr int NV  = WXV * WY;     // 1008
constexpr int NT  = 512;          // == TW*TH, one thread per cell
constexpr int GITER = (NV + NT - 1) / NT;        // 2 geometry iters
constexpr int NG4 = (WXV / 4) * WY;              // 252 float4 col-groups
constexpr int NITEM16 = NG4 * 4;                 // 1008 items per 16-ch pass
constexpr int KIT16 = (NITEM16 + NT - 1) / NT;   // 2

static __device__ __forceinline__ unsigned pkrtz(float a, float b) {
    return __builtin_bit_cast(unsigned, __builtin_amdgcn_cvt_pkrtz(a, b));
}

static __device__ __forceinline__ __half2 h2(unsigned u) {
    union { unsigned u; __half2 h; } x;
    x.u = u;
    return x.h;
}

__global__ __launch_bounds__(NT)
void splat_out(const float* __restrict__ in1,
               const float* __restrict__ flow,
               float* __restrict__ out,
               unsigned* __restrict__ wcnt,
               unsigned* __restrict__ wlist,
               unsigned cap) {
    // mAllS[cell] bit j=(dy+3)*8+(dx+3): source at window offset (dx,dy)
    //   from the cell contributes (dx,dy = source - cell).
    // geomR8[i]: (rx+3) | (ry+3)<<3 (0xFF default; unused by gather then).
    // geomW[i]: .x = half2(w00,w10), .y = half2(w01,w11).
    // valV2[pp*NV + i]: uint2 = channels (cb+4pp .. cb+4pp+3) of source i
    //   for the current 16-channel pass, packed {pkrtz(c0,c1), pkrtz(c2,c3)}.
    __shared__ unsigned long long mAllS[NT];          // 4 KB
    __shared__ unsigned char     geomR8[NV];          // 1 KB
    __shared__ uint2             geomW[NV];           // 8.1 KB
    __shared__ __align__(16) uint2 valV2[4 * NV];     // 32.3 KB (total ~45 KB)

    int bid = blockIdx.x;
    int b = bid & 7;                 // batch -> XCD affinity
    int t = bid >> 3;                // 0..223
    int ty = t / 7;                  // 0..31
    int tx = t - ty * 7;             // 0..6
    int ox = tx * TW, oy = ty * TH;
    int tid = threadIdx.x;
    int qlx = tid & 63, qly = tid >> 6;
    int qx = ox + qlx, qy = oy + qly;

    const float* inb = in1 + (size_t)b * C * HW;

    // ---- staging item addresses (block-static; computed once) ----
    int sOff[KIT16];   // plane-relative offset row*W+gxb, or -1
    int sVb[KIT16];    // LDS vbase
    int sPp[KIT16];    // plane pair index 0..3
#pragma unroll
    for (int k = 0; k < KIT16; ++k) {
        int id = tid + k * NT;
        if (id < NITEM16) {
            int g4 = id % NG4;
            int pp = id / NG4;
            int wy = g4 / (WXV / 4);
            int wv4 = (g4 - wy * (WXV / 4)) * 4;
            int row = min(max(oy + wy - RAD, 0), H - 1);
            int gxb = min(max(ox + wv4 - 4, 0), W - 4);
            sOff[k] = row * W + gxb;
            sVb[k]  = pp * NV + wy * WXV + wv4;
            sPp[k]  = pp;
        } else {
            sOff[k] = -1; sVb[k] = 0; sPp[k] = 0;
        }
    }

    // ---- ISSUE pass-0 global loads NOW (hide under geometry phase) ----
    float4 r0[KIT16][4];
#pragma unroll
    for (int k = 0; k < KIT16; ++k) {
        if (sOff[k] >= 0) {
            const float* base = inb + (size_t)(4 * sPp[k]) * HW + sOff[k];
#pragma unroll
            for (int c = 0; c < 4; ++c)
                r0[k][c] = *reinterpret_cast<const float4*>(base + (size_t)c * HW);
        }
    }

    mAllS[tid] = 0ull;
    __syncthreads();

    // ---- geometry + 1-mask scatter (once per source) + outlier append ----
    const int fbase = b * 2 * HW;
#pragma unroll
    for (int k = 0; k < GITER; ++k) {
        int i = tid + k * NT;
        if (i < NV) {
            int wy = i / WXV, wv = i - wy * WXV;
            int gx = ox + wv - 4;
            int sy = oy + wy - RAD;
            uint2 wd = make_uint2(0u, 0u);
            unsigned gr = 0xFFu;
            if ((unsigned)gx < (unsigned)W && (unsigned)sy < (unsigned)H) {
                int g = sy * W + gx;
                float u = flow[fbase + g];
                float v = flow[fbase + g + HW];
                float txf = (float)gx + u;
                float tyf = (float)sy + v;
                float x0f = floorf(txf), y0f = floorf(tyf);
                int rx = (int)x0f - gx, ry = (int)y0f - sy;
                if (rx >= -RAD && rx <= RAD - 1 && ry >= -RAD && ry <= RAD - 1) {
                    float fx = txf - x0f, fy = tyf - y0f;
                    wd.x = pkrtz((1.f - fx) * (1.f - fy), fx * (1.f - fy));
                    wd.y = pkrtz((1.f - fx) * fy,         fx * fy);
                    gr = (unsigned)(rx + RAD) | ((unsigned)(ry + RAD) << 3);
#pragma unroll
                    for (int corner = 0; corner < 4; ++corner) {
                        int dxx = corner & 1, dyy = corner >> 1;
                        int ccx = gx + rx + dxx - ox;
                        int ccy = sy + ry + dyy - oy;
                        if ((unsigned)ccx < (unsigned)TW &&
                            (unsigned)ccy < (unsigned)TH) {
                            int cell = ccy * TW + ccx;
                            unsigned long long bit =
                                1ull << ((3 - (ry + dyy)) * 8 + (3 - (rx + dxx)));
                            atomicOr(&mAllS[cell], bit);
                        }
                    }
                } else if (wv >= 4 && wv < 4 + TW &&
                           wy >= RAD && wy < RAD + TH) {
                    // unhandled source OWNED by this tile: append exactly once
                    unsigned slot = atomicAdd(wcnt, 1u);
                    if (slot < cap) wlist[slot] = ((unsigned)b << 17) | (unsigned)g;
                }
            }
            geomR8[i] = (unsigned char)gr;
            geomW[i]  = wd;
        }
    }

    // ---- write pass-0 staged values to LDS (loads already in flight) ----
#pragma unroll
    for (int k = 0; k < KIT16; ++k) {
        if (sOff[k] >= 0) {
            uint4* dst = reinterpret_cast<uint4*>(&valV2[sVb[k]]);
            uint4 w0, w1;
            w0.x = pkrtz(r0[k][0].x, r0[k][1].x); w0.y = pkrtz(r0[k][2].x, r0[k][3].x);
            w0.z = pkrtz(r0[k][0].y, r0[k][1].y); w0.w = pkrtz(r0[k][2].y, r0[k][3].y);
            w1.x = pkrtz(r0[k][0].z, r0[k][1].z); w1.y = pkrtz(r0[k][2].z, r0[k][3].z);
            w1.z = pkrtz(r0[k][0].w, r0[k][1].w); w1.w = pkrtz(r0[k][2].w, r0[k][3].w);
            dst[0] = w0;
            dst[1] = w1;
        }
    }
    __syncthreads();

    const unsigned long long m0 = mAllS[tid];
    const int qbase = (qly + RAD) * WXV + (qlx + 4);
    float* outp = out + (size_t)b * C * HW + qy * W + qx;

    // ---- ISSUE pass-1 global loads (hide under gather-0) ----
    float4 r1[KIT16][4];
#pragma unroll
    for (int k = 0; k < KIT16; ++k) {
        if (sOff[k] >= 0) {
            const float* base = inb + (size_t)(16 + 4 * sPp[k]) * HW + sOff[k];
#pragma unroll
            for (int c = 0; c < 4; ++c)
                r1[k][c] = *reinterpret_cast<const float4*>(base + (size_t)c * HW);
        }
    }

    // ---- gather + store one 16-channel pass ----
    auto gather16 = [&](float* o) {
        __half2 acc2[8];
#pragma unroll
        for (int k = 0; k < 8; ++k) acc2[k] = h2(0u);
        unsigned long long m = m0;
        while (m) {
            int j = (int)__builtin_ctzll(m);
            m &= m - 1;
            int wi = qbase + ((j >> 3) - 3) * WXV + ((j & 7) - 3);
            unsigned g8 = geomR8[wi];
            unsigned dxx = 6u - (unsigned)(j & 7) - (g8 & 7u);   // in {0,1}
            unsigned dyy = 6u - (unsigned)(j >> 3) - (g8 >> 3);  // in {0,1}
            uint2 wd2 = geomW[wi];
            unsigned wd = dyy ? wd2.y : wd2.x;
            unsigned hq = (wd >> (16u * dxx)) & 0xFFFFu;
            __half2 w2 = h2(hq | (hq << 16));
#pragma unroll
            for (int pp = 0; pp < 4; ++pp) {
                uint2 vv = valV2[pp * NV + wi];      // ds_read_b64
                acc2[2 * pp + 0] = __hfma2(h2(vv.x), w2, acc2[2 * pp + 0]);
                acc2[2 * pp + 1] = __hfma2(h2(vv.y), w2, acc2[2 * pp + 1]);
            }
        }
#pragma unroll
        for (int pp = 0; pp < 4; ++pp) {
            float2 f01 = __half22float2(acc2[2 * pp + 0]);
            float2 f23 = __half22float2(acc2[2 * pp + 1]);
            o[(size_t)(4 * pp + 0) * HW] = f01.x;
            o[(size_t)(4 * pp + 1) * HW] = f01.y;
            o[(size_t)(4 * pp + 2) * HW] = f23.x;
            o[(size_t)(4 * pp + 3) * HW] = f23.y;
        }
    };

    gather16(outp);                  // channels 0..15 (stores overlap barrier)
    __syncthreads();                 // all pass-0 gathers done

    // ---- write pass-1 staged values to LDS ----
#pragma unroll
    for (int k = 0; k < KIT16; ++k) {
        if (sOff[k] >= 0) {
            uint4* dst = reinterpret_cast<uint4*>(&valV2[sVb[k]]);
            uint4 w0, w1;
            w0.x = pkrtz(r1[k][0].x, r1[k][1].x); w0.y = pkrtz(r1[k][2].x, r1[k][3].x);
            w0.z = pkrtz(r1[k][0].y, r1[k][1].y); w0.w = pkrtz(r1[k][2].y, r1[k][3].y);
            w1.x = pkrtz(r1[k][0].z, r1[k][1].z); w1.y = pkrtz(r1[k][2].z, r1[k][3].z);
            w1.z = pkrtz(r1[k][0].w, r1[k][1].w); w1.w = pkrtz(r1[k][2].w, r1[k][3].w);
            dst[0] = w0;
            dst[1] = w1;
        }
    }
    __syncthreads();

    gather16(outp + (size_t)16 * HW);    // channels 16..31
}

// Outlier handling: list mode if the d_ws list didn't overflow, else full
// scan. Runs AFTER splat_out in stream order -> atomicAdds on plain stores.
__global__ void outlier_combined(const float* __restrict__ in1,
                                 const float* __restrict__ flow,
                                 float* __restrict__ out,
                                 const unsigned* __restrict__ wcnt,
                                 const unsigned* __restrict__ wlist,
                                 unsigned cap) {
    unsigned n = *wcnt;
    if (n <= cap) {
        // ---- list mode: 8 threads per entry (4 channels each) ----
        unsigned total = n * 8u;
        for (unsigned idx = blockIdx.x * blockDim.x + threadIdx.x;
             idx < total; idx += gridDim.x * blockDim.x) {
            unsigned e = wlist[idx >> 3];
            int c0 = (int)(idx & 7u) * 4;
            int bb = (int)(e >> 17);
            int p  = (int)(e & 0x1FFFFu);
            int y = p / W, x = p - y * W;

            float u = flow[(bb * 2 + 0) * HW + p];
            float v = flow[(bb * 2 + 1) * HW + p];
            float txf = (float)x + u;
            float tyf = (float)y + v;
            float fx0 = floorf(txf), fy0 = floorf(tyf);
            int x0 = (int)fx0, y0 = (int)fy0;
            float fx = txf - fx0, fy = tyf - fy0;
            float w00 = (1.0f - fx) * (1.0f - fy);
            float w10 = fx * (1.0f - fy);
            float w01 = (1.0f - fx) * fy;
            float w11 = fx * fy;
            bool vx0 = (x0 >= 0) && (x0 < W);
            bool vx1 = (x0 + 1 >= 0) && (x0 + 1 < W);
            bool vy0 = (y0 >= 0) && (y0 < H);
            bool vy1 = (y0 + 1 >= 0) && (y0 + 1 < H);
            long o00 = (long)y0 * W + x0;

            const float* src  = in1 + (size_t)bb * C * HW + (size_t)c0 * HW + p;
            float*       dstb = out + (size_t)bb * C * HW + (size_t)c0 * HW;
            for (int c = 0; c < 4; ++c) {
                float val = src[(size_t)c * HW];
                float* ob = dstb + (size_t)c * HW;
                if (vx0 && vy0) atomicAdd(ob + o00,         w00 * val);
                if (vx1 && vy0) atomicAdd(ob + o00 + 1,     w10 * val);
                if (vx0 && vy1) atomicAdd(ob + o00 + W,     w01 * val);
                if (vx1 && vy1) atomicAdd(ob + o00 + W + 1, w11 * val);
            }
        }
    } else {
        // ---- fallback: deterministic full scan (list overflowed) ----
        int npix = B * HW;
        for (int idx = blockIdx.x * blockDim.x + threadIdx.x;
             idx < npix; idx += gridDim.x * blockDim.x) {
            int b = idx / HW;
            int p = idx - b * HW;
            int y = p / W, x = p - y * W;
            float u = flow[(b * 2 + 0) * HW + p];
            float v = flow[(b * 2 + 1) * HW + p];
            float txf = (float)x + u;
            float tyf = (float)y + v;
            float fx0 = floorf(txf), fy0 = floorf(tyf);
            int x0 = (int)fx0, y0 = (int)fy0;
            int rx = x0 - x, ry = y0 - y;
            bool handled = (rx >= -RAD) && (rx <= RAD - 1) &&
                           (ry >= -RAD) && (ry <= RAD - 1);
            if (handled) continue;
            float fx = txf - fx0, fy = tyf - fy0;
            float w00 = (1.0f - fx) * (1.0f - fy);
            float w10 = fx * (1.0f - fy);
            float w01 = (1.0f - fx) * fy;
            float w11 = fx * fy;
            bool vx0 = (x0 >= 0) && (x0 < W);
            bool vx1 = (x0 + 1 >= 0) && (x0 + 1 < W);
            bool vy0 = (y0 >= 0) && (y0 < H);
            bool vy1 = (y0 + 1 >= 0) && (y0 + 1 < H);
            long o00 = (long)y0 * W + x0;
            const float* src = in1 + (size_t)b * C * HW + p;
            float* dstb = out + (size_t)b * C * HW;
            for (int c = 0; c < C; ++c) {
                float val = src[(size_t)c * HW];
                float* ob = dstb + (size_t)c * HW;
                if (vx0 && vy0) atomicAdd(ob + o00,         w00 * val);
                if (vx1 && vy0) atomicAdd(ob + o00 + 1,     w10 * val);
                if (vx0 && vy1) atomicAdd(ob + o00 + W,     w01 * val);
                if (vx1 && vy1) atomicAdd(ob + o00 + W + 1, w11 * val);
            }
        }
    }
}

extern "C" void kernel_launch(void* const* d_in, const int* in_sizes, int n_in,
                              void* d_out, int out_size, void* d_ws, size_t ws_size,
                              hipStream_t stream) {
    const float* in1  = (const float*)d_in[0];
    const float* flow = (const float*)d_in[1];
    float* out = (float*)d_out;

    unsigned* wcnt  = (unsigned*)d_ws;
    unsigned* wlist = wcnt + 4;   // 16B-aligned list start
    unsigned cap = 0;
    if (ws_size >= 64) {
        size_t c = ws_size / sizeof(unsigned) - 4;
        cap = (c > 0x7FFFFFFFull) ? 0x7FFFFFFFu : (unsigned)c;
    }

    hipMemsetAsync(wcnt, 0, sizeof(unsigned), stream);

    int nblocks = B * (H / TH) * (W / TW);   // 8 * 32 * 7 = 1792
    splat_out<<<nblocks, NT, 0, stream>>>(in1, flow, out, wcnt, wlist, cap);

    outlier_combined<<<256, 256, 0, stream>>>(in1, flow, out, wcnt, wlist, cap);
}